// Round 18
// baseline (152.468 us; speedup 1.0000x reference)
//
#include <hip/hip_runtime.h>
#include <hip/hip_bf16.h>
#include <math.h>

#define BB 2
#define NQ 4096
#define NC 8192
#define KNN 32
#define WCAP 512
#define QB 2
#define MROWS 64    // QB*KNN
#define BN_EPS 1e-5f

typedef __attribute__((ext_vector_type(8))) short s16x8;
typedef __attribute__((ext_vector_type(4))) float f32x4;

// ---- workspace layout (bytes) ----
#define WS_IDX   0            // int [8192*32]            1 MB
#define WS_CW    1048576      // float [8192*32]          1 MB
#define WS_Z     2097152      // float [8192*128]         4 MB
#define WS_SQ    6291456      // float [8192]             32 KB
#define WS_PCF   6324224      // float4 [16384] sorted    256 KB
#define WS_PIDX  6586368      // int [16384] sorted->orig 64 KB
#define WS_CELL  6651904      // int [16384] cell id      64 KB
#define WS_CCNT  6717440      // int [2*128] counts/cursor 1 KB
#define WS_COFS  6718464      // int [2*128] offsets      1 KB
#define WS_W1    6719488      // bf16 img 128x128         32 KB
#define WS_W2    6752256      // bf16 img 128x128         32 KB
#define WS_W3    6785024      // bf16 img 256x128         64 KB
#define WS_GW1   6850560      // bf16 img 128x256         64 KB
#define WS_GW2   6916096      // bf16 img 64x128          16 KB
#define WS_F3    6932480      // float2 [256]
#define WS_FG1   6934528      // float2 [128]
#define WS_FG2   6935552      // float2 [64]

// 4-bit XOR swizzle: 16 rows -> 16 distinct granules (2-way banks = free).
__device__ inline int swz(int row, int kbyte, int rb) {
    int m = (rb >> 4) - 1; if (m > 15) m = 15;
    return row * rb + (kbyte ^ ((row & m) << 4));
}
__device__ inline unsigned short f2bf(float x) {
    __hip_bfloat16 h = __float2bfloat16(x);
    return *reinterpret_cast<unsigned short*>(&h);
}
__device__ inline float bf2f(unsigned short u) {
    return __uint_as_float(((unsigned)u) << 16);
}
__device__ inline int cell1d(float x) {
    int c = (int)floorf(x * 5.0f);
    return c < 0 ? 0 : (c > 4 ? 4 : c);
}

// ---------------- Kernel 0: prep (weight images, folds, cell ids + counts) ----------------
__device__ inline void mk_img(const float* __restrict__ src, int R, int K, char* dst, int t, int NT)
{
    int rbg = (K * 2) / 16;
    int ng = R * rbg;
    for (int g = t; g < ng; g += NT) {
        int row = g / rbg;
        int b16 = (g - row * rbg) * 16;
        int sb  = b16 ^ ((row & 15) << 4);
        const float* s = src + row * K + sb / 2;
        union { s16x8 v; unsigned short u[8]; } pk;
#pragma unroll
        for (int j = 0; j < 8; ++j) pk.u[j] = f2bf(s[j]);
        *(s16x8*)(dst + row * (K * 2) + b16) = pk.v;
    }
}

__global__ __launch_bounds__(256) void prep_kernel(
    const float* __restrict__ pc,
    const float* __restrict__ w1, const float* __restrict__ w2, const float* __restrict__ w3,
    const float* __restrict__ gw1, const float* __restrict__ gw2,
    const float* __restrict__ g3, const float* __restrict__ b3, const float* __restrict__ m3,
    const float* __restrict__ v3, const float* __restrict__ be3,
    const float* __restrict__ gg1, const float* __restrict__ gb1, const float* __restrict__ gm1,
    const float* __restrict__ gv1, const float* __restrict__ gbe1,
    const float* __restrict__ gg2, const float* __restrict__ gb2, const float* __restrict__ gm2,
    const float* __restrict__ gv2, const float* __restrict__ gbe2,
    char* __restrict__ ws)
{
    const int t = blockIdx.x * 256 + threadIdx.x;
    const int NT = gridDim.x * 256;

    int* cell = (int*)(ws + WS_CELL);
    int* ccnt = (int*)(ws + WS_CCNT);
    for (int i = t; i < BB * NC; i += NT) {
        float x = pc[i*3+0], y = pc[i*3+1], z = pc[i*3+2];
        int c = (cell1d(z)*5 + cell1d(y))*5 + cell1d(x);
        cell[i] = c;
        atomicAdd(&ccnt[(i >> 13)*128 + c], 1);
    }

    mk_img(w1,  128, 128, ws + WS_W1,  t, NT);
    mk_img(w2,  128, 128, ws + WS_W2,  t, NT);
    mk_img(w3,  256, 128, ws + WS_W3,  t, NT);
    mk_img(gw1, 128, 256, ws + WS_GW1, t, NT);
    mk_img(gw2,  64, 128, ws + WS_GW2, t, NT);

    if (t < 256) {
        float s = g3[t] * rsqrtf(v3[t] + BN_EPS);
        ((float2*)(ws + WS_F3))[t] = make_float2(s, s * (b3[t] - m3[t]) + be3[t]);
    }
    if (t < 128) {
        float s = gg1[t] * rsqrtf(gv1[t] + BN_EPS);
        ((float2*)(ws + WS_FG1))[t] = make_float2(s, s * (gb1[t] - gm1[t]) + gbe1[t]);
    }
    if (t < 64) {
        float s = gg2[t] * rsqrtf(gv2[t] + BN_EPS);
        ((float2*)(ws + WS_FG2))[t] = make_float2(s, s * (gb2[t] - gm2[t]) + gbe2[t]);
    }
}

// ---------------- Kernel 0b: prefix scan of cell counts (2 waves, 1 block) ----------------
__global__ __launch_bounds__(128) void scan_kernel(char* __restrict__ ws)
{
    int* ccnt = (int*)(ws + WS_CCNT);
    int* cofs = (int*)(ws + WS_COFS);
    const int wv = threadIdx.x >> 6, lane = threadIdx.x & 63;
    const int base = wv * 128;
    int a = (lane < 125) ? ccnt[base + lane] : 0;
    int b = (64 + lane < 125) ? ccnt[base + 64 + lane] : 0;
    int ai = a, bi = b;
    for (int d = 1; d < 64; d <<= 1) {
        int t = __shfl_up(ai, d, 64);
        if (lane >= d) ai += t;
    }
    int totA = __shfl(ai, 63, 64);
    for (int d = 1; d < 64; d <<= 1) {
        int t = __shfl_up(bi, d, 64);
        if (lane >= d) bi += t;
    }
    int exA = ai - a;
    int exB = totA + bi - b;
    cofs[base + lane] = exA;       cofs[base + 64 + lane] = exB;
    ccnt[base + lane] = exA;       ccnt[base + 64 + lane] = exB;   // scatter cursor
}

// ---------------- Kernel 0c: scatter points into cell-sorted order ----------------
__global__ __launch_bounds__(256) void scatter_kernel(
    const float* __restrict__ pc, char* __restrict__ ws)
{
    const int i = blockIdx.x * 256 + threadIdx.x;
    if (i >= BB * NC) return;
    const int b = i >> 13, loc = i & (NC - 1);
    int* cell = (int*)(ws + WS_CELL);
    int* cur  = (int*)(ws + WS_CCNT);
    float4* pcf = (float4*)(ws + WS_PCF);
    int*    pidx = (int*)(ws + WS_PIDX);
    int c = cell[i];
    int pos = atomicAdd(&cur[b*128 + c], 1);
    float x = pc[i*3+0], y = pc[i*3+1], z = pc[i*3+2];
    float w = (x*x + y*y) + z*z;
    pcf[(size_t)b*NC + pos]  = make_float4(x, y, z, w);
    pidx[(size_t)b*NC + pos] = loc;
}

// ---- single-u64 compare-exchange across lanes ----
__device__ inline void cmpxu(unsigned long long& k, int j, bool up) {
    unsigned long long ok = __shfl_xor(k, j, 64);
    bool lower = ((threadIdx.x & 63) & j) == 0;
    bool take = (lower == up) ? (k > ok) : (k < ok);
    if (take) k = ok;
}
__device__ inline void sortasc64(unsigned long long& k) {
    const int lane = threadIdx.x & 63;
    for (int kk = 2; kk <= 64; kk <<= 1)
        for (int j = kk >> 1; j > 0; j >>= 1)
            cmpxu(k, j, (lane & kk) == 0);
}
__device__ inline void sortdesc64(unsigned long long& k) {
    const int lane = threadIdx.x & 63;
    for (int kk = 2; kk <= 64; kk <<= 1)
        for (int j = kk >> 1; j > 0; j >>= 1)
            cmpxu(k, j, (lane & kk) != 0);
}
__device__ inline void merge128(unsigned long long& k0, unsigned long long& k1) {
    if (k0 > k1) { unsigned long long t = k0; k0 = k1; k1 = t; }
#pragma unroll
    for (int j = 32; j > 0; j >>= 1) { cmpxu(k0, j, true); cmpxu(k1, j, true); }
}
__device__ inline void cmpx64(unsigned long long& k, int& p, int j, bool up) {
    unsigned long long ok = __shfl_xor(k, j, 64);
    int op = __shfl_xor(p, j, 64);
    bool lower = ((threadIdx.x & 63) & j) == 0;
    bool gt = (k > ok) || (k == ok && p > op);
    bool take = (lower == up) ? gt : !gt;
    if (take) { k = ok; p = op; }
}
__device__ inline void sortasc64kp(unsigned long long& k, int& p) {
    const int lane = threadIdx.x & 63;
    for (int kk = 2; kk <= 64; kk <<= 1)
        for (int j = kk >> 1; j > 0; j >>= 1)
            cmpx64(k, p, j, (lane & kk) == 0);
}

// ---------------- Kernel 1: binned radius top-32, 1 wave per query ----------------
__global__ __launch_bounds__(256) void knn_kernel(
    const float* __restrict__ pq, const float* __restrict__ pc,
    const float4* __restrict__ pcf, const int* __restrict__ pidx,
    const int* __restrict__ cofs,
    int* __restrict__ idx_out, float* __restrict__ cw_out)
{
    __shared__ unsigned long long kbuf[4][WCAP];   // 16 KB

    const int tid = threadIdx.x, lane = tid & 63, w = tid >> 6;
    const int gq = blockIdx.x * 4 + w;            // wave-private query
    const int b = gq >> 12;

    const float qxf = pq[gq*3+0], qyf = pq[gq*3+1], qzf = pq[gq*3+2];
    const double qx = (double)qxf, qy = (double)qyf, qz = (double)qzf;
    const double sq = qx*qx + qy*qy + qz*qz;
    const float  sqf = (float)sq;
    const double R2d = 0.2 * 0.2;
    const float  R2f = 0.04f + 1e-4f;

    const float4* pcfb = pcf + (size_t)b * NC;
    const int*    pidb = pidx + (size_t)b * NC;
    const int*    cb   = cofs + b * 128;
    const float*  pcb  = pc + (size_t)b * NC * 3;

    int xlo = (int)floorf((qxf - 0.2f) * 5.0f - 1e-3f); xlo = xlo < 0 ? 0 : xlo;
    int xhi = (int)floorf((qxf + 0.2f) * 5.0f + 1e-3f); xhi = xhi > 4 ? 4 : xhi;
    int ylo = (int)floorf((qyf - 0.2f) * 5.0f - 1e-3f); ylo = ylo < 0 ? 0 : ylo;
    int yhi = (int)floorf((qyf + 0.2f) * 5.0f + 1e-3f); yhi = yhi > 4 ? 4 : yhi;
    int zlo = (int)floorf((qzf - 0.2f) * 5.0f - 1e-3f); zlo = zlo < 0 ? 0 : zlo;
    int zhi = (int)floorf((qzf + 0.2f) * 5.0f + 1e-3f); zhi = zhi > 4 ? 4 : zhi;

    const unsigned long long lt = (lane == 63) ? ~0ULL >> 1 : (1ULL << lane) - 1;
    int cnt = 0;
    for (int zi = zlo; zi <= zhi; ++zi) {
        for (int yi = ylo; yi <= yhi; ++yi) {
            int row = (zi*5 + yi)*5;
            int s = cb[row + xlo], e = cb[row + xhi + 1];

            float4 cd; int pv = 0;
            {
                int t = s + lane;
                if (t < e) { cd = pcfb[t]; pv = pidb[t]; }
            }
            for (int t0 = s; t0 < e; t0 += 64) {
                float4 cur = cd; int pcur = pv;
                bool hcur = (t0 + lane) < e;
                int tn = t0 + 64 + lane;
                if (tn < e) { cd = pcfb[tn]; pv = pidb[tn]; }
                bool pred = false;
                unsigned long long key = ~0ULL;
                if (hcur) {
                    float dot = (qxf*cur.x + qyf*cur.y) + qzf*cur.z;
                    float d   = (sqf - 2.0f*dot) + cur.w;
                    pred = (d <= R2f);
                    if (pred) {
                        float dc = fmaxf(d, 0.0f);
                        key = ((unsigned long long)__float_as_uint(dc) << 32)
                            | (unsigned)pcur;
                    }
                }
                unsigned long long mask = __ballot(pred);
                if (pred) {
                    int pos = cnt + __popcll(mask & lt);
                    if (pos < WCAP) kbuf[w][pos] = key;
                }
                cnt += __popcll(mask);
            }
        }
    }
    if (cnt > WCAP) cnt = WCAP;

    unsigned long long k0 = (lane < cnt)      ? kbuf[w][lane]      : ~0ULL;
    unsigned long long k1 = (64 + lane < cnt) ? kbuf[w][64 + lane] : ~0ULL;
    sortasc64(k0);
    sortdesc64(k1);
    merge128(k0, k1);
    int consumed = 128;
    while (consumed < cnt) {
        int i1 = consumed + lane;
        k1 = (i1 < cnt) ? kbuf[w][i1] : ~0ULL;
        sortdesc64(k1);
        merge128(k0, k1);
        consumed += 64;
    }

    unsigned long long kf = ~0ULL;
    int pf = 0x7fffffff;
    if (k0 != ~0ULL) {
        int n = (int)(k0 & 0xffffffffULL);
        double cx = (double)pcb[n*3+0];
        double cy = (double)pcb[n*3+1];
        double cz = (double)pcb[n*3+2];
        double dot = qx*cx + qy*cy + qz*cz;
        double sc  = cx*cx + cy*cy + cz*cz;
        double d   = (sq - 2.0*dot) + sc;
        if (d <= R2d) {
            double dc = d < 0.0 ? 0.0 : d;
            kf = (unsigned long long)__double_as_longlong(dc);
            pf = n;
        }
    }
    sortasc64kp(kf, pf);

    if (lane < KNN) {
        int id = 0; float c = 0.0f;
        if (kf != ~0ULL) {
            id = pf;
            double d = __longlong_as_double((long long)kf);
            if (d > 0.0 && d <= 0.2) {
                double cw = 0.5 * (cos(d * 15.707963267948966) + 1.0);
                c = (float)cw;
            }
        }
        idx_out[gq*KNN + lane] = id;
        cw_out[gq*KNN + lane]  = c;
    }
}

// ---------------- Kernel 2a: front, QB=2, 256 threads, 3 blocks/CU ----------------
__global__ __launch_bounds__(256, 3) void front_kernel(
    const float* __restrict__ pq, const float* __restrict__ pc, const float* __restrict__ hc,
    const float* __restrict__ w_xyz, const float* __restrict__ b_xyz,
    const float* __restrict__ b1, const float* __restrict__ g1,
    const float* __restrict__ be1, const float* __restrict__ m1, const float* __restrict__ v1,
    const float* __restrict__ b2, const float* __restrict__ g2,
    const float* __restrict__ be2, const float* __restrict__ m2, const float* __restrict__ v2,
    const char* __restrict__ w1img, const char* __restrict__ w2img,
    const int* __restrict__ idx_in, const float* __restrict__ cw_in,
    float* __restrict__ z_buf, float* __restrict__ sq_buf)
{
    __shared__ __align__(16) char smem[52480];
    char*  Ab   = smem;                          // 16 KB (64 rows x 256 B)
    char*  Wb   = smem + 16384;                  // 32 KB
    float* Prel = (float*)(smem + 49152);        // 64*3
    float* Cw   = (float*)(smem + 49920);        // 64
    int*   Sidx = (int*)  (smem + 50176);        // 64
    float* Sfd  = (float*)(smem + 50432);        // [4][128]

    const int tid = threadIdx.x;
    const int qbase = blockIdx.x * QB;
    const int b = qbase >> 12;
    const float* pcb = pc + (size_t)b * NC * 3;
    const float* hcb = hc + (size_t)b * NC * 64;

    if (tid < MROWS) {
        int id = idx_in[qbase*KNN + tid];
        Sidx[tid] = id;
        Cw[tid]   = cw_in[qbase*KNN + tid];
        int gq = qbase + (tid >> 5);
        Prel[tid*3+0] = pcb[id*3+0] - pq[gq*3+0];
        Prel[tid*3+1] = pcb[id*3+1] - pq[gq*3+1];
        Prel[tid*3+2] = pcb[id*3+2] - pq[gq*3+2];
    }
    __syncthreads();

    for (int p = tid; p < MROWS*16; p += 256) {
        int row = p >> 4, seg = p & 15;
        float vals[8];
        if (seg >= 8) {
            const float* src = hcb + (size_t)Sidx[row]*64 + (seg-8)*8;
            float4 u0 = *(const float4*)src;
            float4 u1 = *(const float4*)(src+4);
            vals[0]=u0.x; vals[1]=u0.y; vals[2]=u0.z; vals[3]=u0.w;
            vals[4]=u1.x; vals[5]=u1.y; vals[6]=u1.z; vals[7]=u1.w;
        } else {
            float px = Prel[row*3+0], py = Prel[row*3+1], pz = Prel[row*3+2];
            int c0 = seg*8;
#pragma unroll
            for (int j = 0; j < 8; ++j) {
                int c = c0 + j;
                vals[j] = px*w_xyz[c*3+0] + py*w_xyz[c*3+1] + pz*w_xyz[c*3+2] + b_xyz[c];
            }
        }
        union { s16x8 v; unsigned short u[8]; } pk;
#pragma unroll
        for (int j = 0; j < 8; ++j) pk.u[j] = f2bf(vals[j]);
        *(s16x8*)(Ab + swz(row, seg*16, 256)) = pk.v;
    }
    if (tid < 128) {
        int j = tid;
        float s0 = g1[j] * rsqrtf(v1[j] + BN_EPS);
        Sfd[0*128 + j] = s0; Sfd[1*128 + j] = s0*(b1[j]-m1[j]) + be1[j];
        float s1 = g2[j] * rsqrtf(v2[j] + BN_EPS);
        Sfd[2*128 + j] = s1; Sfd[3*128 + j] = s1*(b2[j]-m2[j]) + be2[j];
    }
    if (tid < QB) {
        float s = 0.0f;
        for (int i = 0; i < KNN; ++i) s += Cw[tid*KNN + i];
        sq_buf[qbase + tid] = s;
    }

    const int l = tid & 63, w = tid >> 6;     // 4 waves, 16 rows each
    const int r0 = w * 16, cl = l & 15, q4 = l >> 4;

#pragma unroll 1
    for (int L = 0; L < 2; ++L) {
        const s16x8* wimg = (const s16x8*)(L ? w2img : w1img);
        s16x8* Wv = (s16x8*)Wb;
        for (int p = tid; p < 2048; p += 256) Wv[p] = wimg[p];
        __syncthreads();

        f32x4 acc[8];
#pragma unroll
        for (int nt = 0; nt < 8; ++nt) acc[nt] = (f32x4){0.f,0.f,0.f,0.f};
#pragma unroll
        for (int kk = 0; kk < 4; ++kk) {
            int kbyte = kk*64 + q4*16;
            s16x8 a0 = *(const s16x8*)(Ab + swz(r0 + cl, kbyte, 256));
#pragma unroll
            for (int nt = 0; nt < 8; ++nt) {
                s16x8 bwv = *(const s16x8*)(Wb + swz(nt*16 + cl, kbyte, 256));
                acc[nt] = __builtin_amdgcn_mfma_f32_16x16x32_bf16(a0, bwv, acc[nt], 0, 0, 0);
            }
        }
#pragma unroll
        for (int nt = 0; nt < 8; ++nt) {
            int j = nt*16 + cl;
            float s = Sfd[(L*2+0)*128 + j], t = Sfd[(L*2+1)*128 + j];
#pragma unroll
            for (int r = 0; r < 4; ++r) {
                int row = r0 + q4*4 + r;
                float x = fmaxf(acc[nt][r]*s + t, 0.0f);
                *(unsigned short*)(Ab + swz(row, j*2, 256)) = f2bf(x);
            }
        }
        __syncthreads();
    }

    {
        int q = tid >> 7, col = tid & 127;    // q = 0..1
        float s = 0.0f;
#pragma unroll
        for (int i = 0; i < KNN; ++i) {
            unsigned short u = *(const unsigned short*)(Ab + swz(q*KNN + i, col*2, 256));
            s += Cw[q*KNN + i] * bf2f(u);
        }
        z_buf[(size_t)(qbase + q)*128 + col] = s;
    }
}

// ---------------- Kernel 2b: tail GEMM chain (M=64 queries/block) ----------------
__global__ __launch_bounds__(256) void tail_kernel(
    const char* __restrict__ w3img, const char* __restrict__ gw1img, const char* __restrict__ gw2img,
    const float2* __restrict__ f3, const float2* __restrict__ fg1, const float2* __restrict__ fg2,
    const float* __restrict__ z_buf, const float* __restrict__ sq_buf,
    const float* __restrict__ gw3, const float* __restrict__ gb3,
    float* __restrict__ out)
{
    __shared__ __align__(16) char smem[123136];
    char* A1 = smem;
    char* A2 = smem + 16384;
    char* A4 = smem + 49152;
    char* Wb = smem + 57344;
    float* Ssm = (float*)(smem + 122880);

    const int tid = threadIdx.x;
    const int q0 = blockIdx.x * 64;

    for (int g = tid; g < 1024; g += 256) {
        int row = g >> 4, seg = g & 15;
        const float* zs = z_buf + (size_t)(q0 + row)*128 + seg*8;
        float4 u0 = *(const float4*)zs;
        float4 u1 = *(const float4*)(zs+4);
        union { s16x8 v; unsigned short u[8]; } pk;
        pk.u[0]=f2bf(u0.x); pk.u[1]=f2bf(u0.y); pk.u[2]=f2bf(u0.z); pk.u[3]=f2bf(u0.w);
        pk.u[4]=f2bf(u1.x); pk.u[5]=f2bf(u1.y); pk.u[6]=f2bf(u1.z); pk.u[7]=f2bf(u1.w);
        *(s16x8*)(A1 + swz(row, seg*16, 256)) = pk.v;
    }
    for (int p = tid; p < 4096; p += 256) ((s16x8*)Wb)[p] = ((const s16x8*)w3img)[p];
    if (tid < 64) Ssm[tid] = sq_buf[q0 + tid];
    __syncthreads();

    const int l = tid & 63, w = tid >> 6;
    const int r0 = w*16, cl = l & 15, q4 = l >> 4;

    {
        f32x4 acc[16];
#pragma unroll
        for (int nt = 0; nt < 16; ++nt) acc[nt] = (f32x4){0.f,0.f,0.f,0.f};
#pragma unroll
        for (int kk = 0; kk < 4; ++kk) {
            int kbyte = kk*64 + q4*16;
            s16x8 a0 = *(const s16x8*)(A1 + swz(r0 + cl, kbyte, 256));
#pragma unroll
            for (int nt = 0; nt < 16; ++nt) {
                s16x8 bwv = *(const s16x8*)(Wb + swz(nt*16 + cl, kbyte, 256));
                acc[nt] = __builtin_amdgcn_mfma_f32_16x16x32_bf16(a0, bwv, acc[nt], 0, 0, 0);
            }
        }
#pragma unroll
        for (int nt = 0; nt < 16; ++nt) {
            int j = nt*16 + cl;
            float2 f = f3[j];
#pragma unroll
            for (int r = 0; r < 4; ++r) {
                int row = r0 + q4*4 + r;
                float S = Ssm[row];
                float x = f.x*acc[nt][r] + S*f.y;
                *(unsigned short*)(A2 + swz(row, j*2, 512)) = f2bf(x);
            }
        }
    }
    __syncthreads();
    for (int p = tid; p < 4096; p += 256) ((s16x8*)Wb)[p] = ((const s16x8*)gw1img)[p];
    __syncthreads();

    {
        f32x4 acc[8];
#pragma unroll
        for (int nt = 0; nt < 8; ++nt) acc[nt] = (f32x4){0.f,0.f,0.f,0.f};
#pragma unroll
        for (int kk = 0; kk < 8; ++kk) {
            int kbyte = kk*64 + q4*16;
            s16x8 a0 = *(const s16x8*)(A2 + swz(r0 + cl, kbyte, 512));
#pragma unroll
            for (int nt = 0; nt < 8; ++nt) {
                s16x8 bwv = *(const s16x8*)(Wb + swz(nt*16 + cl, kbyte, 512));
                acc[nt] = __builtin_amdgcn_mfma_f32_16x16x32_bf16(a0, bwv, acc[nt], 0, 0, 0);
            }
        }
#pragma unroll
        for (int nt = 0; nt < 8; ++nt) {
            int j = nt*16 + cl;
            float2 f = fg1[j];
#pragma unroll
            for (int r = 0; r < 4; ++r) {
                int row = r0 + q4*4 + r;
                float x = fmaxf(f.x*acc[nt][r] + f.y, 0.0f);
                *(unsigned short*)(A1 + swz(row, j*2, 256)) = f2bf(x);
            }
        }
    }
    __syncthreads();
    for (int p = tid; p < 1024; p += 256) ((s16x8*)Wb)[p] = ((const s16x8*)gw2img)[p];
    __syncthreads();

    {
        f32x4 acc[4];
#pragma unroll
        for (int nt = 0; nt < 4; ++nt) acc[nt] = (f32x4){0.f,0.f,0.f,0.f};
#pragma unroll
        for (int kk = 0; kk < 4; ++kk) {
            int kbyte = kk*64 + q4*16;
            s16x8 a0 = *(const s16x8*)(A1 + swz(r0 + cl, kbyte, 256));
#pragma unroll
            for (int nt = 0; nt < 4; ++nt) {
                s16x8 bwv = *(const s16x8*)(Wb + swz(nt*16 + cl, kbyte, 256));
                acc[nt] = __builtin_amdgcn_mfma_f32_16x16x32_bf16(a0, bwv, acc[nt], 0, 0, 0);
            }
        }
#pragma unroll
        for (int nt = 0; nt < 4; ++nt) {
            int j = nt*16 + cl;
            float2 f = fg2[j];
#pragma unroll
            for (int r = 0; r < 4; ++r) {
                int row = r0 + q4*4 + r;
                float x = fmaxf(f.x*acc[nt][r] + f.y, 0.0f);
                *(unsigned short*)(A4 + swz(row, j*2, 128)) = f2bf(x);
            }
        }
    }
    __syncthreads();

    if (tid < 192) {
        int q = tid / 3, jj = tid - q*3;
        const float* wr = gw3 + jj*64;
        float s = 0.0f;
        for (int k = 0; k < 64; ++k) {
            unsigned short u = *(const unsigned short*)(A4 + swz(q, k*2, 128));
            s += bf2f(u) * wr[k];
        }
        out[(size_t)(q0 + q)*3 + jj] = s + gb3[jj];
    }
}

extern "C" void kernel_launch(void* const* d_in, const int* in_sizes, int n_in,
                              void* d_out, int out_size, void* d_ws, size_t ws_size,
                              hipStream_t stream)
{
    const float* pq    = (const float*)d_in[0];
    const float* pc    = (const float*)d_in[1];
    const float* hc    = (const float*)d_in[2];
    const float* w_xyz = (const float*)d_in[3];
    const float* b_xyz = (const float*)d_in[4];
    const float* w1    = (const float*)d_in[5];
    const float* b1    = (const float*)d_in[6];
    const float* g1    = (const float*)d_in[7];
    const float* be1   = (const float*)d_in[8];
    const float* m1    = (const float*)d_in[9];
    const float* v1    = (const float*)d_in[10];
    const float* w2    = (const float*)d_in[11];
    const float* b2    = (const float*)d_in[12];
    const float* g2    = (const float*)d_in[13];
    const float* be2   = (const float*)d_in[14];
    const float* m2    = (const float*)d_in[15];
    const float* v2    = (const float*)d_in[16];
    const float* w3    = (const float*)d_in[17];
    const float* b3    = (const float*)d_in[18];
    const float* g3    = (const float*)d_in[19];
    const float* be3   = (const float*)d_in[20];
    const float* m3    = (const float*)d_in[21];
    const float* v3    = (const float*)d_in[22];
    const float* gw1   = (const float*)d_in[23];
    const float* gb1   = (const float*)d_in[24];
    const float* gg1   = (const float*)d_in[25];
    const float* gbe1  = (const float*)d_in[26];
    const float* gm1   = (const float*)d_in[27];
    const float* gv1   = (const float*)d_in[28];
    const float* gw2   = (const float*)d_in[29];
    const float* gb2   = (const float*)d_in[30];
    const float* gg2   = (const float*)d_in[31];
    const float* gbe2  = (const float*)d_in[32];
    const float* gm2   = (const float*)d_in[33];
    const float* gv2   = (const float*)d_in[34];
    const float* gw3   = (const float*)d_in[35];
    const float* gb3   = (const float*)d_in[36];

    char* ws = (char*)d_ws;
    int*   idx_buf = (int*)(ws + WS_IDX);
    float* cw_buf  = (float*)(ws + WS_CW);
    float* z_buf   = (float*)(ws + WS_Z);
    float* sq_buf  = (float*)(ws + WS_SQ);

    hipMemsetAsync(ws + WS_CCNT, 0, 1024, stream);

    prep_kernel<<<64, 256, 0, stream>>>(pc, w1, w2, w3, gw1, gw2,
        g3, b3, m3, v3, be3, gg1, gb1, gm1, gv1, gbe1, gg2, gb2, gm2, gv2, gbe2, ws);

    scan_kernel<<<1, 128, 0, stream>>>(ws);

    scatter_kernel<<<(BB*NC + 255)/256, 256, 0, stream>>>(pc, ws);

    knn_kernel<<<(BB*NQ)/4, 256, 0, stream>>>(pq, pc,
        (const float4*)(ws + WS_PCF), (const int*)(ws + WS_PIDX),
        (const int*)(ws + WS_COFS), idx_buf, cw_buf);

    front_kernel<<<(BB*NQ)/QB, 256, 0, stream>>>(pq, pc, hc, w_xyz, b_xyz,
        b1, g1, be1, m1, v1, b2, g2, be2, m2, v2,
        ws + WS_W1, ws + WS_W2, idx_buf, cw_buf, z_buf, sq_buf);

    tail_kernel<<<(BB*NQ)/64, 256, 0, stream>>>(
        ws + WS_W3, ws + WS_GW1, ws + WS_GW2,
        (const float2*)(ws + WS_F3), (const float2*)(ws + WS_FG1), (const float2*)(ws + WS_FG2),
        z_buf, sq_buf, gw3, gb3, (float*)d_out);
}

// Round 19
// 140.557 us; speedup vs baseline: 1.0847x; 1.0847x over previous
//
#include <hip/hip_runtime.h>
#include <hip/hip_bf16.h>
#include <math.h>

#define BB 2
#define NQ 4096
#define NC 8192
#define KNN 32
#define WCAP 512
#define QB 4
#define MROWS 128   // QB*KNN
#define BN_EPS 1e-5f

typedef __attribute__((ext_vector_type(8))) short s16x8;
typedef __attribute__((ext_vector_type(4))) float f32x4;

// ---- workspace layout (bytes) ----
#define WS_IDX   0            // int [8192*32]            1 MB
#define WS_CW    1048576      // float [8192*32]          1 MB
#define WS_Z     2097152      // float [8192*128]         4 MB
#define WS_SQ    6291456      // float [8192]             32 KB
#define WS_PCF   6324224      // float4 [16384] sorted    256 KB
#define WS_PIDX  6586368      // int [16384] sorted->orig 64 KB
#define WS_CELL  6651904      // int [16384] cell id      64 KB
#define WS_CCNT  6717440      // int [2*128] counts/cursor 1 KB
#define WS_COFS  6718464      // int [2*128] offsets      1 KB
#define WS_W1    6719488      // bf16 img 128x128         32 KB
#define WS_W2    6752256      // bf16 img 128x128         32 KB
#define WS_W3    6785024      // bf16 img 256x128         64 KB
#define WS_GW1   6850560      // bf16 img 128x256         64 KB
#define WS_GW2   6916096      // bf16 img 64x128          16 KB
#define WS_F3    6932480      // float2 [256]
#define WS_FG1   6934528      // float2 [128]
#define WS_FG2   6935552      // float2 [64]

// 4-bit XOR swizzle: 16 rows -> 16 distinct granules (2-way banks = free).
__device__ inline int swz(int row, int kbyte, int rb) {
    int m = (rb >> 4) - 1; if (m > 15) m = 15;
    return row * rb + (kbyte ^ ((row & m) << 4));
}
__device__ inline unsigned short f2bf(float x) {
    __hip_bfloat16 h = __float2bfloat16(x);
    return *reinterpret_cast<unsigned short*>(&h);
}
__device__ inline float bf2f(unsigned short u) {
    return __uint_as_float(((unsigned)u) << 16);
}
__device__ inline int cell1d(float x) {
    int c = (int)floorf(x * 5.0f);
    return c < 0 ? 0 : (c > 4 ? 4 : c);
}

// ---------------- Kernel 0: prep (weight images, folds, cell ids + counts) ----------------
__device__ inline void mk_img(const float* __restrict__ src, int R, int K, char* dst, int t, int NT)
{
    int rbg = (K * 2) / 16;
    int ng = R * rbg;
    for (int g = t; g < ng; g += NT) {
        int row = g / rbg;
        int b16 = (g - row * rbg) * 16;
        int sb  = b16 ^ ((row & 15) << 4);
        const float* s = src + row * K + sb / 2;
        union { s16x8 v; unsigned short u[8]; } pk;
#pragma unroll
        for (int j = 0; j < 8; ++j) pk.u[j] = f2bf(s[j]);
        *(s16x8*)(dst + row * (K * 2) + b16) = pk.v;
    }
}

__global__ __launch_bounds__(256) void prep_kernel(
    const float* __restrict__ pc,
    const float* __restrict__ w1, const float* __restrict__ w2, const float* __restrict__ w3,
    const float* __restrict__ gw1, const float* __restrict__ gw2,
    const float* __restrict__ g3, const float* __restrict__ b3, const float* __restrict__ m3,
    const float* __restrict__ v3, const float* __restrict__ be3,
    const float* __restrict__ gg1, const float* __restrict__ gb1, const float* __restrict__ gm1,
    const float* __restrict__ gv1, const float* __restrict__ gbe1,
    const float* __restrict__ gg2, const float* __restrict__ gb2, const float* __restrict__ gm2,
    const float* __restrict__ gv2, const float* __restrict__ gbe2,
    char* __restrict__ ws)
{
    const int t = blockIdx.x * 256 + threadIdx.x;
    const int NT = gridDim.x * 256;

    int* cell = (int*)(ws + WS_CELL);
    int* ccnt = (int*)(ws + WS_CCNT);
    for (int i = t; i < BB * NC; i += NT) {
        float x = pc[i*3+0], y = pc[i*3+1], z = pc[i*3+2];
        int c = (cell1d(z)*5 + cell1d(y))*5 + cell1d(x);
        cell[i] = c;
        atomicAdd(&ccnt[(i >> 13)*128 + c], 1);
    }

    mk_img(w1,  128, 128, ws + WS_W1,  t, NT);
    mk_img(w2,  128, 128, ws + WS_W2,  t, NT);
    mk_img(w3,  256, 128, ws + WS_W3,  t, NT);
    mk_img(gw1, 128, 256, ws + WS_GW1, t, NT);
    mk_img(gw2,  64, 128, ws + WS_GW2, t, NT);

    if (t < 256) {
        float s = g3[t] * rsqrtf(v3[t] + BN_EPS);
        ((float2*)(ws + WS_F3))[t] = make_float2(s, s * (b3[t] - m3[t]) + be3[t]);
    }
    if (t < 128) {
        float s = gg1[t] * rsqrtf(gv1[t] + BN_EPS);
        ((float2*)(ws + WS_FG1))[t] = make_float2(s, s * (gb1[t] - gm1[t]) + gbe1[t]);
    }
    if (t < 64) {
        float s = gg2[t] * rsqrtf(gv2[t] + BN_EPS);
        ((float2*)(ws + WS_FG2))[t] = make_float2(s, s * (gb2[t] - gm2[t]) + gbe2[t]);
    }
}

// ---------------- Kernel 0b: prefix scan of cell counts (2 waves, 1 block) ----------------
__global__ __launch_bounds__(128) void scan_kernel(char* __restrict__ ws)
{
    int* ccnt = (int*)(ws + WS_CCNT);
    int* cofs = (int*)(ws + WS_COFS);
    const int wv = threadIdx.x >> 6, lane = threadIdx.x & 63;
    const int base = wv * 128;
    int a = (lane < 125) ? ccnt[base + lane] : 0;
    int b = (64 + lane < 125) ? ccnt[base + 64 + lane] : 0;
    int ai = a, bi = b;
    for (int d = 1; d < 64; d <<= 1) {
        int t = __shfl_up(ai, d, 64);
        if (lane >= d) ai += t;
    }
    int totA = __shfl(ai, 63, 64);
    for (int d = 1; d < 64; d <<= 1) {
        int t = __shfl_up(bi, d, 64);
        if (lane >= d) bi += t;
    }
    int exA = ai - a;
    int exB = totA + bi - b;
    cofs[base + lane] = exA;       cofs[base + 64 + lane] = exB;
    ccnt[base + lane] = exA;       ccnt[base + 64 + lane] = exB;   // scatter cursor
}

// ---------------- Kernel 0c: scatter points into cell-sorted order ----------------
__global__ __launch_bounds__(256) void scatter_kernel(
    const float* __restrict__ pc, char* __restrict__ ws)
{
    const int i = blockIdx.x * 256 + threadIdx.x;
    if (i >= BB * NC) return;
    const int b = i >> 13, loc = i & (NC - 1);
    int* cell = (int*)(ws + WS_CELL);
    int* cur  = (int*)(ws + WS_CCNT);
    float4* pcf = (float4*)(ws + WS_PCF);
    int*    pidx = (int*)(ws + WS_PIDX);
    int c = cell[i];
    int pos = atomicAdd(&cur[b*128 + c], 1);
    float x = pc[i*3+0], y = pc[i*3+1], z = pc[i*3+2];
    float w = (x*x + y*y) + z*z;
    pcf[(size_t)b*NC + pos]  = make_float4(x, y, z, w);
    pidx[(size_t)b*NC + pos] = loc;
}

// ---- single-u64 compare-exchange across lanes ----
__device__ inline void cmpxu(unsigned long long& k, int j, bool up) {
    unsigned long long ok = __shfl_xor(k, j, 64);
    bool lower = ((threadIdx.x & 63) & j) == 0;
    bool take = (lower == up) ? (k > ok) : (k < ok);
    if (take) k = ok;
}
__device__ inline void sortasc64(unsigned long long& k) {
    const int lane = threadIdx.x & 63;
    for (int kk = 2; kk <= 64; kk <<= 1)
        for (int j = kk >> 1; j > 0; j >>= 1)
            cmpxu(k, j, (lane & kk) == 0);
}
__device__ inline void sortdesc64(unsigned long long& k) {
    const int lane = threadIdx.x & 63;
    for (int kk = 2; kk <= 64; kk <<= 1)
        for (int j = kk >> 1; j > 0; j >>= 1)
            cmpxu(k, j, (lane & kk) != 0);
}
__device__ inline void merge128(unsigned long long& k0, unsigned long long& k1) {
    if (k0 > k1) { unsigned long long t = k0; k0 = k1; k1 = t; }
#pragma unroll
    for (int j = 32; j > 0; j >>= 1) { cmpxu(k0, j, true); cmpxu(k1, j, true); }
}
__device__ inline void cmpx64(unsigned long long& k, int& p, int j, bool up) {
    unsigned long long ok = __shfl_xor(k, j, 64);
    int op = __shfl_xor(p, j, 64);
    bool lower = ((threadIdx.x & 63) & j) == 0;
    bool gt = (k > ok) || (k == ok && p > op);
    bool take = (lower == up) ? gt : !gt;
    if (take) { k = ok; p = op; }
}
__device__ inline void sortasc64kp(unsigned long long& k, int& p) {
    const int lane = threadIdx.x & 63;
    for (int kk = 2; kk <= 64; kk <<= 1)
        for (int j = kk >> 1; j > 0; j >>= 1)
            cmpx64(k, p, j, (lane & kk) == 0);
}

// ---------------- Kernel 1: binned radius top-32, 1 wave per query ----------------
__global__ __launch_bounds__(256) void knn_kernel(
    const float* __restrict__ pq, const float* __restrict__ pc,
    const float4* __restrict__ pcf, const int* __restrict__ pidx,
    const int* __restrict__ cofs,
    int* __restrict__ idx_out, float* __restrict__ cw_out)
{
    __shared__ unsigned long long kbuf[4][WCAP];   // 16 KB

    const int tid = threadIdx.x, lane = tid & 63, w = tid >> 6;
    const int gq = blockIdx.x * 4 + w;            // wave-private query
    const int b = gq >> 12;

    const float qxf = pq[gq*3+0], qyf = pq[gq*3+1], qzf = pq[gq*3+2];
    const double qx = (double)qxf, qy = (double)qyf, qz = (double)qzf;
    const double sq = qx*qx + qy*qy + qz*qz;
    const float  sqf = (float)sq;
    const double R2d = 0.2 * 0.2;
    const float  R2f = 0.04f + 1e-4f;

    const float4* pcfb = pcf + (size_t)b * NC;
    const int*    pidb = pidx + (size_t)b * NC;
    const int*    cb   = cofs + b * 128;
    const float*  pcb  = pc + (size_t)b * NC * 3;

    int xlo = (int)floorf((qxf - 0.2f) * 5.0f - 1e-3f); xlo = xlo < 0 ? 0 : xlo;
    int xhi = (int)floorf((qxf + 0.2f) * 5.0f + 1e-3f); xhi = xhi > 4 ? 4 : xhi;
    int ylo = (int)floorf((qyf - 0.2f) * 5.0f - 1e-3f); ylo = ylo < 0 ? 0 : ylo;
    int yhi = (int)floorf((qyf + 0.2f) * 5.0f + 1e-3f); yhi = yhi > 4 ? 4 : yhi;
    int zlo = (int)floorf((qzf - 0.2f) * 5.0f - 1e-3f); zlo = zlo < 0 ? 0 : zlo;
    int zhi = (int)floorf((qzf + 0.2f) * 5.0f + 1e-3f); zhi = zhi > 4 ? 4 : zhi;

    // pass 1: f32 filter; composite key (f32 dist bits << 32 | pid) ballot-compacted.
    // UNIFORM trip count: every lane executes every __ballot.
    const unsigned long long lt = (lane == 63) ? ~0ULL >> 1 : (1ULL << lane) - 1;
    int cnt = 0;
    for (int zi = zlo; zi <= zhi; ++zi) {
        for (int yi = ylo; yi <= yhi; ++yi) {
            int row = (zi*5 + yi)*5;
            int s = cb[row + xlo], e = cb[row + xhi + 1];
            for (int t0 = s; t0 < e; t0 += 64) {
                int t = t0 + lane;
                bool pred = false;
                unsigned long long key = ~0ULL;
                if (t < e) {
                    float4 cd = pcfb[t];
                    float dot = (qxf*cd.x + qyf*cd.y) + qzf*cd.z;
                    float d   = (sqf - 2.0f*dot) + cd.w;
                    pred = (d <= R2f);
                    if (pred) {
                        float dc = fmaxf(d, 0.0f);
                        key = ((unsigned long long)__float_as_uint(dc) << 32)
                            | (unsigned)pidb[t];
                    }
                }
                unsigned long long mask = __ballot(pred);
                if (pred) {
                    int pos = cnt + __popcll(mask & lt);
                    if (pos < WCAP) kbuf[w][pos] = key;
                }
                cnt += __popcll(mask);
            }
        }
    }
    if (cnt > WCAP) cnt = WCAP;

    // streaming top-64 by f32 composite key (wave-private registers)
    unsigned long long k0 = (lane < cnt)      ? kbuf[w][lane]      : ~0ULL;
    unsigned long long k1 = (64 + lane < cnt) ? kbuf[w][64 + lane] : ~0ULL;
    sortasc64(k0);
    sortdesc64(k1);
    merge128(k0, k1);
    int consumed = 128;
    while (consumed < cnt) {
        int i1 = consumed + lane;
        k1 = (i1 < cnt) ? kbuf[w][i1] : ~0ULL;
        sortdesc64(k1);
        merge128(k0, k1);      // k0 keeps the 64 smallest seen so far
        consumed += 64;
    }

    // exact fp64 rekey of the f32-top-64 (identical op order to reference path)
    unsigned long long kf = ~0ULL;
    int pf = 0x7fffffff;
    if (k0 != ~0ULL) {
        int n = (int)(k0 & 0xffffffffULL);
        double cx = (double)pcb[n*3+0];
        double cy = (double)pcb[n*3+1];
        double cz = (double)pcb[n*3+2];
        double dot = qx*cx + qy*cy + qz*cz;
        double sc  = cx*cx + cy*cy + cz*cz;
        double d   = (sq - 2.0*dot) + sc;
        if (d <= R2d) {
            double dc = d < 0.0 ? 0.0 : d;
            kf = (unsigned long long)__double_as_longlong(dc);
            pf = n;
        }
    }
    sortasc64kp(kf, pf);

    if (lane < KNN) {
        int id = 0; float c = 0.0f;
        if (kf != ~0ULL) {
            id = pf;
            double d = __longlong_as_double((long long)kf);
            if (d > 0.0 && d <= 0.2) {
                double cw = 0.5 * (cos(d * 15.707963267948966) + 1.0);
                c = (float)cw;
            }
        }
        idx_out[gq*KNN + lane] = id;
        cw_out[gq*KNN + lane]  = c;
    }
}

// ---------------- Kernel 2a: front (gather + L1 + L2 MFMA + c-weighted reduce) ----------------
__global__ __launch_bounds__(512, 4) void front_kernel(
    const float* __restrict__ pq, const float* __restrict__ pc, const float* __restrict__ hc,
    const float* __restrict__ w_xyz, const float* __restrict__ b_xyz,
    const float* __restrict__ b1, const float* __restrict__ g1,
    const float* __restrict__ be1, const float* __restrict__ m1, const float* __restrict__ v1,
    const float* __restrict__ b2, const float* __restrict__ g2,
    const float* __restrict__ be2, const float* __restrict__ m2, const float* __restrict__ v2,
    const char* __restrict__ w1img, const char* __restrict__ w2img,
    const int* __restrict__ idx_in, const float* __restrict__ cw_in,
    float* __restrict__ z_buf, float* __restrict__ sq_buf)
{
    __shared__ __align__(16) char smem[70144];
    char*  Ab   = smem;
    char*  Wb   = smem + 32768;
    float* Prel = (float*)(smem + 65536);
    float* Cw   = (float*)(smem + 67072);
    int*   Sidx = (int*)  (smem + 67584);
    float* Sfd  = (float*)(smem + 68096);

    const int tid = threadIdx.x;
    const int qbase = blockIdx.x * QB;
    const int b = qbase >> 12;
    const float* pcb = pc + (size_t)b * NC * 3;
    const float* hcb = hc + (size_t)b * NC * 64;

    if (tid < MROWS) {
        int id = idx_in[qbase*KNN + tid];
        Sidx[tid] = id;
        Cw[tid]   = cw_in[qbase*KNN + tid];
        int gq = qbase + (tid >> 5);
        Prel[tid*3+0] = pcb[id*3+0] - pq[gq*3+0];
        Prel[tid*3+1] = pcb[id*3+1] - pq[gq*3+1];
        Prel[tid*3+2] = pcb[id*3+2] - pq[gq*3+2];
    }
    __syncthreads();

    for (int p = tid; p < MROWS*16; p += 512) {
        int row = p >> 4, seg = p & 15;
        float vals[8];
        if (seg >= 8) {
            const float* src = hcb + (size_t)Sidx[row]*64 + (seg-8)*8;
            float4 u0 = *(const float4*)src;
            float4 u1 = *(const float4*)(src+4);
            vals[0]=u0.x; vals[1]=u0.y; vals[2]=u0.z; vals[3]=u0.w;
            vals[4]=u1.x; vals[5]=u1.y; vals[6]=u1.z; vals[7]=u1.w;
        } else {
            float px = Prel[row*3+0], py = Prel[row*3+1], pz = Prel[row*3+2];
            int c0 = seg*8;
#pragma unroll
            for (int j = 0; j < 8; ++j) {
                int c = c0 + j;
                vals[j] = px*w_xyz[c*3+0] + py*w_xyz[c*3+1] + pz*w_xyz[c*3+2] + b_xyz[c];
            }
        }
        union { s16x8 v; unsigned short u[8]; } pk;
#pragma unroll
        for (int j = 0; j < 8; ++j) pk.u[j] = f2bf(vals[j]);
        *(s16x8*)(Ab + swz(row, seg*16, 256)) = pk.v;
    }
    if (tid < 128) {
        int j = tid;
        float s0 = g1[j] * rsqrtf(v1[j] + BN_EPS);
        Sfd[0*128 + j] = s0; Sfd[1*128 + j] = s0*(b1[j]-m1[j]) + be1[j];
        float s1 = g2[j] * rsqrtf(v2[j] + BN_EPS);
        Sfd[2*128 + j] = s1; Sfd[3*128 + j] = s1*(b2[j]-m2[j]) + be2[j];
    }
    if (tid < QB) {
        float s = 0.0f;
        for (int i = 0; i < KNN; ++i) s += Cw[tid*KNN + i];
        sq_buf[qbase + tid] = s;
    }

    const int l = tid & 63, w = tid >> 6;
    const int r0 = w * 16, cl = l & 15, q4 = l >> 4;

#pragma unroll 1
    for (int L = 0; L < 2; ++L) {
        const s16x8* wimg = (const s16x8*)(L ? w2img : w1img);
        s16x8* Wv = (s16x8*)Wb;
        for (int p = tid; p < 2048; p += 512) Wv[p] = wimg[p];
        __syncthreads();

        f32x4 acc[8];
#pragma unroll
        for (int nt = 0; nt < 8; ++nt) acc[nt] = (f32x4){0.f,0.f,0.f,0.f};
#pragma unroll
        for (int kk = 0; kk < 4; ++kk) {
            int kbyte = kk*64 + q4*16;
            s16x8 a0 = *(const s16x8*)(Ab + swz(r0 + cl, kbyte, 256));
#pragma unroll
            for (int nt = 0; nt < 8; ++nt) {
                s16x8 bwv = *(const s16x8*)(Wb + swz(nt*16 + cl, kbyte, 256));
                acc[nt] = __builtin_amdgcn_mfma_f32_16x16x32_bf16(a0, bwv, acc[nt], 0, 0, 0);
            }
        }
#pragma unroll
        for (int nt = 0; nt < 8; ++nt) {
            int j = nt*16 + cl;
            float s = Sfd[(L*2+0)*128 + j], t = Sfd[(L*2+1)*128 + j];
#pragma unroll
            for (int r = 0; r < 4; ++r) {
                int row = r0 + q4*4 + r;
                float x = fmaxf(acc[nt][r]*s + t, 0.0f);
                *(unsigned short*)(Ab + swz(row, j*2, 256)) = f2bf(x);
            }
        }
        __syncthreads();
    }

    {
        int q = tid >> 7, col = tid & 127;
        float s = 0.0f;
#pragma unroll
        for (int i = 0; i < KNN; ++i) {
            unsigned short u = *(const unsigned short*)(Ab + swz(q*KNN + i, col*2, 256));
            s += Cw[q*KNN + i] * bf2f(u);
        }
        z_buf[(size_t)(qbase + q)*128 + col] = s;
    }
}

// ---------------- Kernel 2b: tail GEMM chain (M=64 queries/block) ----------------
__global__ __launch_bounds__(256) void tail_kernel(
    const char* __restrict__ w3img, const char* __restrict__ gw1img, const char* __restrict__ gw2img,
    const float2* __restrict__ f3, const float2* __restrict__ fg1, const float2* __restrict__ fg2,
    const float* __restrict__ z_buf, const float* __restrict__ sq_buf,
    const float* __restrict__ gw3, const float* __restrict__ gb3,
    float* __restrict__ out)
{
    __shared__ __align__(16) char smem[123136];
    char* A1 = smem;
    char* A2 = smem + 16384;
    char* A4 = smem + 49152;
    char* Wb = smem + 57344;
    float* Ssm = (float*)(smem + 122880);

    const int tid = threadIdx.x;
    const int q0 = blockIdx.x * 64;

    for (int g = tid; g < 1024; g += 256) {
        int row = g >> 4, seg = g & 15;
        const float* zs = z_buf + (size_t)(q0 + row)*128 + seg*8;
        float4 u0 = *(const float4*)zs;
        float4 u1 = *(const float4*)(zs+4);
        union { s16x8 v; unsigned short u[8]; } pk;
        pk.u[0]=f2bf(u0.x); pk.u[1]=f2bf(u0.y); pk.u[2]=f2bf(u0.z); pk.u[3]=f2bf(u0.w);
        pk.u[4]=f2bf(u1.x); pk.u[5]=f2bf(u1.y); pk.u[6]=f2bf(u1.z); pk.u[7]=f2bf(u1.w);
        *(s16x8*)(A1 + swz(row, seg*16, 256)) = pk.v;
    }
    for (int p = tid; p < 4096; p += 256) ((s16x8*)Wb)[p] = ((const s16x8*)w3img)[p];
    if (tid < 64) Ssm[tid] = sq_buf[q0 + tid];
    __syncthreads();

    const int l = tid & 63, w = tid >> 6;
    const int r0 = w*16, cl = l & 15, q4 = l >> 4;

    {
        f32x4 acc[16];
#pragma unroll
        for (int nt = 0; nt < 16; ++nt) acc[nt] = (f32x4){0.f,0.f,0.f,0.f};
#pragma unroll
        for (int kk = 0; kk < 4; ++kk) {
            int kbyte = kk*64 + q4*16;
            s16x8 a0 = *(const s16x8*)(A1 + swz(r0 + cl, kbyte, 256));
#pragma unroll
            for (int nt = 0; nt < 16; ++nt) {
                s16x8 bwv = *(const s16x8*)(Wb + swz(nt*16 + cl, kbyte, 256));
                acc[nt] = __builtin_amdgcn_mfma_f32_16x16x32_bf16(a0, bwv, acc[nt], 0, 0, 0);
            }
        }
#pragma unroll
        for (int nt = 0; nt < 16; ++nt) {
            int j = nt*16 + cl;
            float2 f = f3[j];
#pragma unroll
            for (int r = 0; r < 4; ++r) {
                int row = r0 + q4*4 + r;
                float S = Ssm[row];
                float x = f.x*acc[nt][r] + S*f.y;
                *(unsigned short*)(A2 + swz(row, j*2, 512)) = f2bf(x);
            }
        }
    }
    __syncthreads();
    for (int p = tid; p < 4096; p += 256) ((s16x8*)Wb)[p] = ((const s16x8*)gw1img)[p];
    __syncthreads();

    {
        f32x4 acc[8];
#pragma unroll
        for (int nt = 0; nt < 8; ++nt) acc[nt] = (f32x4){0.f,0.f,0.f,0.f};
#pragma unroll
        for (int kk = 0; kk < 8; ++kk) {
            int kbyte = kk*64 + q4*16;
            s16x8 a0 = *(const s16x8*)(A2 + swz(r0 + cl, kbyte, 512));
#pragma unroll
            for (int nt = 0; nt < 8; ++nt) {
                s16x8 bwv = *(const s16x8*)(Wb + swz(nt*16 + cl, kbyte, 512));
                acc[nt] = __builtin_amdgcn_mfma_f32_16x16x32_bf16(a0, bwv, acc[nt], 0, 0, 0);
            }
        }
#pragma unroll
        for (int nt = 0; nt < 8; ++nt) {
            int j = nt*16 + cl;
            float2 f = fg1[j];
#pragma unroll
            for (int r = 0; r < 4; ++r) {
                int row = r0 + q4*4 + r;
                float x = fmaxf(f.x*acc[nt][r] + f.y, 0.0f);
                *(unsigned short*)(A1 + swz(row, j*2, 256)) = f2bf(x);
            }
        }
    }
    __syncthreads();
    for (int p = tid; p < 1024; p += 256) ((s16x8*)Wb)[p] = ((const s16x8*)gw2img)[p];
    __syncthreads();

    {
        f32x4 acc[4];
#pragma unroll
        for (int nt = 0; nt < 4; ++nt) acc[nt] = (f32x4){0.f,0.f,0.f,0.f};
#pragma unroll
        for (int kk = 0; kk < 4; ++kk) {
            int kbyte = kk*64 + q4*16;
            s16x8 a0 = *(const s16x8*)(A1 + swz(r0 + cl, kbyte, 256));
#pragma unroll
            for (int nt = 0; nt < 4; ++nt) {
                s16x8 bwv = *(const s16x8*)(Wb + swz(nt*16 + cl, kbyte, 256));
                acc[nt] = __builtin_amdgcn_mfma_f32_16x16x32_bf16(a0, bwv, acc[nt], 0, 0, 0);
            }
        }
#pragma unroll
        for (int nt = 0; nt < 4; ++nt) {
            int j = nt*16 + cl;
            float2 f = fg2[j];
#pragma unroll
            for (int r = 0; r < 4; ++r) {
                int row = r0 + q4*4 + r;
                float x = fmaxf(f.x*acc[nt][r] + f.y, 0.0f);
                *(unsigned short*)(A4 + swz(row, j*2, 128)) = f2bf(x);
            }
        }
    }
    __syncthreads();

    if (tid < 192) {
        int q = tid / 3, jj = tid - q*3;
        const float* wr = gw3 + jj*64;
        float s = 0.0f;
        for (int k = 0; k < 64; ++k) {
            unsigned short u = *(const unsigned short*)(A4 + swz(q, k*2, 128));
            s += bf2f(u) * wr[k];
        }
        out[(size_t)(q0 + q)*3 + jj] = s + gb3[jj];
    }
}

extern "C" void kernel_launch(void* const* d_in, const int* in_sizes, int n_in,
                              void* d_out, int out_size, void* d_ws, size_t ws_size,
                              hipStream_t stream)
{
    const float* pq    = (const float*)d_in[0];
    const float* pc    = (const float*)d_in[1];
    const float* hc    = (const float*)d_in[2];
    const float* w_xyz = (const float*)d_in[3];
    const float* b_xyz = (const float*)d_in[4];
    const float* w1    = (const float*)d_in[5];
    const float* b1    = (const float*)d_in[6];
    const float* g1    = (const float*)d_in[7];
    const float* be1   = (const float*)d_in[8];
    const float* m1    = (const float*)d_in[9];
    const float* v1    = (const float*)d_in[10];
    const float* w2    = (const float*)d_in[11];
    const float* b2    = (const float*)d_in[12];
    const float* g2    = (const float*)d_in[13];
    const float* be2   = (const float*)d_in[14];
    const float* m2    = (const float*)d_in[15];
    const float* v2    = (const float*)d_in[16];
    const float* w3    = (const float*)d_in[17];
    const float* b3    = (const float*)d_in[18];
    const float* g3    = (const float*)d_in[19];
    const float* be3   = (const float*)d_in[20];
    const float* m3    = (const float*)d_in[21];
    const float* v3    = (const float*)d_in[22];
    const float* gw1   = (const float*)d_in[23];
    const float* gb1   = (const float*)d_in[24];
    const float* gg1   = (const float*)d_in[25];
    const float* gbe1  = (const float*)d_in[26];
    const float* gm1   = (const float*)d_in[27];
    const float* gv1   = (const float*)d_in[28];
    const float* gw2   = (const float*)d_in[29];
    const float* gb2   = (const float*)d_in[30];
    const float* gg2   = (const float*)d_in[31];
    const float* gbe2  = (const float*)d_in[32];
    const float* gm2   = (const float*)d_in[33];
    const float* gv2   = (const float*)d_in[34];
    const float* gw3   = (const float*)d_in[35];
    const float* gb3   = (const float*)d_in[36];

    char* ws = (char*)d_ws;
    int*   idx_buf = (int*)(ws + WS_IDX);
    float* cw_buf  = (float*)(ws + WS_CW);
    float* z_buf   = (float*)(ws + WS_Z);
    float* sq_buf  = (float*)(ws + WS_SQ);

    hipMemsetAsync(ws + WS_CCNT, 0, 1024, stream);

    prep_kernel<<<64, 256, 0, stream>>>(pc, w1, w2, w3, gw1, gw2,
        g3, b3, m3, v3, be3, gg1, gb1, gm1, gv1, gbe1, gg2, gb2, gm2, gv2, gbe2, ws);

    scan_kernel<<<1, 128, 0, stream>>>(ws);

    scatter_kernel<<<(BB*NC + 255)/256, 256, 0, stream>>>(pc, ws);

    knn_kernel<<<(BB*NQ)/4, 256, 0, stream>>>(pq, pc,
        (const float4*)(ws + WS_PCF), (const int*)(ws + WS_PIDX),
        (const int*)(ws + WS_COFS), idx_buf, cw_buf);

    front_kernel<<<(BB*NQ)/QB, 512, 0, stream>>>(pq, pc, hc, w_xyz, b_xyz,
        b1, g1, be1, m1, v1, b2, g2, be2, m2, v2,
        ws + WS_W1, ws + WS_W2, idx_buf, cw_buf, z_buf, sq_buf);

    tail_kernel<<<(BB*NQ)/64, 256, 0, stream>>>(
        ws + WS_W3, ws + WS_GW1, ws + WS_GW2,
        (const float2*)(ws + WS_F3), (const float2*)(ws + WS_FG1), (const float2*)(ws + WS_FG2),
        z_buf, sq_buf, gw3, gb3, (float*)d_out);
}